// Round 17
// baseline (137.552 us; speedup 1.0000x reference)
//
#include <hip/hip_runtime.h>
#include <hip/hip_cooperative_groups.h>
#include <math.h>

namespace cg = cooperative_groups;

#define NPTS 32768
#define CAPP 192
#define CAPC 57
#define SCALE ((float)(256.0 / (2.0 * M_PI)))

typedef __attribute__((ext_vector_type(8))) short short8b;   // 8 bf16
typedef __attribute__((ext_vector_type(4))) float f32x4;

static __device__ __forceinline__ unsigned short f2bf(float x) {
    unsigned u = __float_as_uint(x);
    return (unsigned short)((u + 0x7fffu + ((u >> 16) & 1u)) >> 16);
}

static __device__ __forceinline__ float bessel_i0f(float x) {
    float hx2 = 0.25f * x * x;
    float t = 1.0f, s = 1.0f;
#pragma unroll
    for (int m = 1; m <= 30; ++m) { t *= hx2 * (1.0f / ((float)m * (float)m)); s += t; }
    return s;
}

// ================= single cooperative mega-kernel, 256 blocks x 512 =================
__global__ __launch_bounds__(512) void k_mega(
        const float* __restrict__ coords, const float* __restrict__ values,
        unsigned short* __restrict__ Sfrag, float* __restrict__ wxy,
        unsigned* __restrict__ tileCount, unsigned* __restrict__ bins,
        float* __restrict__ vt, unsigned short* __restrict__ Gt,
        float* __restrict__ out) {
    __shared__ __align__(16) char smem[41984];
    cg::grid_group grid = cg::this_grid();
    int blk = blockIdx.x;
    int t = threadIdx.x;

    // ---------- P0: zero tileCount (1024*16 u32) ----------
    {
        int gid = blk * 512 + t;
        if (gid < 16384) tileCount[gid] = 0u;
    }
    grid.sync();

    // ---------- P1: front ----------
    if (blk < 64) {
        // prep: one point per thread, k = blk*512 + t
        int k = blk * 512 + t;
        const float inv_i0a = 1.0f / bessel_i0f(14.04f);  // constant-folds
        float2 cv = *(const float2*)&coords[2 * k];
        float gmx = cv.x * SCALE;
        float gmy = cv.y * SCALE;
        float bxf = floorf(gmx - 3.0f), byf = floorf(gmy - 3.0f);
        float wl[12];
#pragma unroll
        for (int j = 0; j < 6; ++j) {
            float ux = gmx - (bxf + (float)(j + 1));
            float rx = ux * (1.0f / 3.0f);
            float argx = 1.0f - rx * rx;
            wl[j] = (argx > 0.0f) ? bessel_i0f(14.04f * sqrtf(argx)) * inv_i0a : 0.0f;
            float uy = gmy - (byf + (float)(j + 1));
            float ry = uy * (1.0f / 3.0f);
            float argy = 1.0f - ry * ry;
            wl[6 + j] = (argy > 0.0f) ? bessel_i0f(14.04f * sqrtf(argy)) * inv_i0a : 0.0f;
        }
        float4* wp = (float4*)&wxy[k * 12];
        wp[0] = *(const float4*)&wl[0];
        wp[1] = *(const float4*)&wl[4];
        wp[2] = *(const float4*)&wl[8];
        int x0 = (((int)bxf) + 1 + 512) & 255;
        int y0 = (((int)byf) + 1 + 512) & 255;
        int tx0 = x0 >> 3, tx1 = ((x0 + 5) & 255) >> 3;
        int ty0 = y0 >> 3, ty1 = ((y0 + 5) & 255) >> 3;
        int nx = (tx1 == tx0) ? 1 : 2;
        int ny = (ty1 == ty0) ? 1 : 2;
        int txs[2] = {tx0, tx1}, tys[2] = {ty0, ty1};
        for (int i = 0; i < nx; ++i)
            for (int j = 0; j < ny; ++j) {
                int tl = txs[i] * 32 + tys[j];
                unsigned ex = (unsigned)((x0 - 8 * txs[i] + 256) & 255);
                unsigned ey = (unsigned)((y0 - 8 * tys[j] + 256) & 255);
                unsigned pos = atomicAdd(&tileCount[tl * 16], 1u);   // line-padded
                if (pos < CAPP) bins[tl * CAPP + pos] = ((unsigned)k << 16) | (ex << 8) | ey;
            }
    } else if (blk < 192) {
        // transpose: kbase = (blk-64)*256, all 512 threads
        float (*tile)[257] = (float(*)[257])smem;
        int kbase = (blk - 64) * 256;
        int col = t & 255;
        for (int img = t >> 8; img < 32; img += 2)
            tile[img][col] = values[img * NPTS + kbase + col];
        __syncthreads();
        int img = t & 31;
        int k0 = t >> 5;                   // 0..15
        for (int r = 0; r < 16; ++r) {
            int kl = k0 + r * 16;          // 0..255
            vt[(kbase + kl) * 32 + img] = tile[img][kl];
        }
    } else if (blk < 200) {
        // setup slice s = blk-192 (all 512 threads hit the barriers)
        float* axf = (float*)smem;                  // 128 f32
        float2* sSh = (float2*)(smem + 512);        // 256 float2
        if (t < 128) {
            const float inv_i0a = 1.0f / bessel_i0f(14.04f);
            float om = ((float)t - 63.5f) * (1.0f / 256.0f);
            float pj = (float)M_PI * 6.0f * om;
            float tt = sqrtf(14.04f * 14.04f - pj * pj);       // always real
            float kbft = 6.0f * (sinhf(tt) / tt) * inv_i0a;
            axf[t] = 1.0f / kbft;                              // apodization 1D
        }
        __syncthreads();
        if (t < 256) {
            float sw, cw;
            __sincosf((float)t * (float)(2.0 * M_PI / 256.0), &sw, &cw);
            float zr = 1.0f, zi = 0.0f, re = 0.0f, im = 0.0f;
            for (int x = 0; x < 128; ++x) {
                float a = axf[x];                // broadcast, conflict-free
                re = fmaf(a, zr, re);
                im = fmaf(a, zi, im);
                float nzr = zr * cw - zi * sw;
                zi = fmaf(zr, sw, zi * cw);
                zr = nzr;
            }
            sSh[t] = make_float2(re, im);
        }
        __syncthreads();
        int s = blk - 192;
        for (int idx = s * 4096 + t; idx < (s + 1) * 4096; idx += 512) {
            int i   = idx & 7;
            int ln  = (idx >> 3) & 63;
            int ks  = (idx >> 9) & 7;
            int tl  = idx >> 12;
            int si = (32 * ks + 8 * (ln >> 4) + i - 2 * (16 * tl + (ln & 15))) & 255;
            float2 sv = sSh[si];
            Sfrag[idx]         = f2bf(sv.x);
            Sfrag[32768 + idx] = f2bf(sv.y);
            Sfrag[65536 + idx] = f2bf(-sv.y);
        }
    }
    grid.sync();

    // ---------- P2: tile gather -> Gt (2 sub-blocks x 2 tiles) ----------
    {
        int s = t >> 8;                    // sub-block 0/1
        int tt = t & 255;
        char* base = smem + s * 20736;
        unsigned* cnt = (unsigned*)base;                       // 64
        unsigned* lists = cnt + 64;                            // 64*CAPC
        unsigned* bsh = lists + 64 * CAPC;                     // CAPP
        unsigned short (*gsh)[40] = (unsigned short(*)[40])(bsh + CAPP);
        for (int ti = 0; ti < 2; ++ti) {
            int tile = blk * 4 + s * 2 + ti;
            int TX = tile >> 5, TY = tile & 31;
            __syncthreads();               // protect LDS reuse across iterations/phases
            if (tt < 64) cnt[tt] = 0u;
            unsigned n = tileCount[tile * 16];
            if (n > CAPP) n = CAPP;
            for (int p = tt; p < (int)n; p += 256) bsh[p] = bins[tile * CAPP + p];
            __syncthreads();
            // stage A: build per-cell entry lists
            int total = (int)n * 6;
            for (int task = tt; task < total; task += 256) {
                int pi = task / 6;
                int jx = task - pi * 6;
                unsigned en = bsh[pi];
                int ex = (int)((en >> 8) & 255u);
                int ey = (int)(en & 255u);
                if (((ex + jx) & 255) < 8) {
                    unsigned k = en >> 16;
                    float wxv = wxy[k * 12 + jx];
                    int lx = ((ex + jx) & 7) << 3;
                    unsigned kq = k << 16;
                    int jy0, jy1;
                    if (ey <= 7) { jy0 = 0; jy1 = (7 - ey < 5) ? 7 - ey : 5; }
                    else         { jy0 = 256 - ey; jy1 = 5; }
                    for (int jy = jy0; jy <= jy1; ++jy) {
                        float w = wxv * wxy[k * 12 + 6 + jy];
                        unsigned q = (unsigned)(w * 65535.0f + 0.5f);
                        if (q > 65535u) q = 65535u;
                        int cl = lx | ((ey + jy) & 7);
                        unsigned pos = atomicAdd(&cnt[cl], 1u);
                        if (pos < CAPC) lists[cl * CAPC + pos] = kq | q;
                    }
                }
            }
            __syncthreads();
            // stage B: thread owns (cell c, 8 images)
            int c = tt >> 2;
            int ib = (tt & 3) * 8;
            unsigned nc = cnt[c];
            if (nc > CAPC) nc = CAPC;
            float acc0 = 0, acc1 = 0, acc2 = 0, acc3 = 0, acc4 = 0, acc5 = 0, acc6 = 0, acc7 = 0;
            for (unsigned e = 0; e < nc; ++e) {
                unsigned en = lists[c * CAPC + e];
                float w = (float)(en & 0xFFFFu) * (1.0f / 65535.0f);
                const float* vp = &vt[(en >> 16) * 32 + ib];
                float4 va = *(const float4*)vp;
                float4 vb = *(const float4*)(vp + 4);
                acc0 += w * va.x; acc1 += w * va.y; acc2 += w * va.z; acc3 += w * va.w;
                acc4 += w * vb.x; acc5 += w * vb.y; acc6 += w * vb.z; acc7 += w * vb.w;
            }
            {
                unsigned short* gp = &gsh[c][ib];
                gp[0] = f2bf(acc0); gp[1] = f2bf(acc1); gp[2] = f2bf(acc2); gp[3] = f2bf(acc3);
                gp[4] = f2bf(acc4); gp[5] = f2bf(acc5); gp[6] = f2bf(acc6); gp[7] = f2bf(acc7);
            }
            __syncthreads();
            // writeout: (img = tt>>3, vrow = tt&7): 16B contiguous store
            {
                int img = tt >> 3;
                int vr = tt & 7;
                short8b row;
#pragma unroll
                for (int uu = 0; uu < 8; ++uu)
                    row[uu] = (short)gsh[(uu << 3) | vr][img];
                *(short8b*)&Gt[img * 65536 + (((TY << 3) + vr) << 8) + (TX << 3)] = row;
            }
        }
    }
    grid.sync();

    // ---------- P3: MFMA spectral stage (8-wave, verbatim R12/R16 math) ----------
    {
        unsigned short* T1 = (unsigned short*)smem;   // [2][16][264] flat
        int band = blk >> 5;               // 0..7
        int img = blk & 31;                // XCD = img%8 -> all 8 band-blocks of an img share an XCD
        int lane = t & 63;
        int w = t >> 6;                    // wave 0..7
        int g4 = lane >> 4;
        int l15 = lane & 15;

        // ---- stage 1 ----
        {
            int var = w >> 2;              // 0: re, 1: im
            const unsigned short* sf = Sfrag + var * 32768 + band * 4096 + lane * 8;
            short8b a[8];
#pragma unroll
            for (int ks = 0; ks < 8; ++ks)
                a[ks] = *(const short8b*)(sf + ks * 512);
            const unsigned short* gimg = Gt + img * 65536 + 8 * g4;
#pragma unroll
            for (int j = 0; j < 4; ++j) {
                int vtile = (w & 3) + j * 4;
                int v0 = vtile * 16;
                const unsigned short* gb = gimg + (v0 + l15) * 256;
                f32x4 acc = {0.f, 0.f, 0.f, 0.f};
#pragma unroll
                for (int ks = 0; ks < 8; ++ks) {
                    short8b b = *(const short8b*)(gb + ks * 32);
                    acc = __builtin_amdgcn_mfma_f32_16x16x32_bf16(a[ks], b, acc, 0, 0, 0);
                }
                int vcol = v0 + l15;
#pragma unroll
                for (int r = 0; r < 4; ++r) {
                    int p = g4 * 4 + r;
                    T1[var * 4224 + p * 264 + (vcol ^ ((p & 7) << 3))] = f2bf(acc[r]);
                }
            }
        }
        __syncthreads();

        // ---- stage 2 ----
        {
            int qt = w;
            const unsigned short* sfq = Sfrag + qt * 4096 + lane * 8;
            int swz = (l15 & 7) << 3;
            f32x4 accR = {0.f, 0.f, 0.f, 0.f}, accI = {0.f, 0.f, 0.f, 0.f};
#pragma unroll
            for (int ks = 0; ks < 8; ++ks) {
                int vidx = (32 * ks + 8 * g4) ^ swz;
                short8b aR = *(const short8b*)&T1[0 * 4224 + l15 * 264 + vidx];
                short8b aI = *(const short8b*)&T1[1 * 4224 + l15 * 264 + vidx];
                short8b bR = *(const short8b*)(sfq + ks * 512);
                short8b bI = *(const short8b*)(sfq + 32768 + ks * 512);
                short8b bN = *(const short8b*)(sfq + 65536 + ks * 512);
                accR = __builtin_amdgcn_mfma_f32_16x16x32_bf16(aR, bR, accR, 0, 0, 0);
                accR = __builtin_amdgcn_mfma_f32_16x16x32_bf16(aI, bN, accR, 0, 0, 0);
                accI = __builtin_amdgcn_mfma_f32_16x16x32_bf16(aR, bI, accI, 0, 0, 0);
                accI = __builtin_amdgcn_mfma_f32_16x16x32_bf16(aI, bR, accI, 0, 0, 0);
            }
            int q = qt * 16 + l15;
            int b_ = img >> 2, c_ = img & 3;
            int obase = ((b_ ^ 4) * 4 + (c_ ^ 2)) * 128;
#pragma unroll
            for (int r = 0; r < 4; ++r) {
                int p = band * 16 + g4 * 4 + r;
                float re = accR[r], im = accI[r];
                out[((obase + (p ^ 64)) << 7) + (q ^ 64)] = sqrtf(re * re + im * im);
            }
        }
    }
}

extern "C" void kernel_launch(void* const* d_in, const int* in_sizes, int n_in,
                              void* d_out, int out_size, void* d_ws, size_t ws_size,
                              hipStream_t stream) {
    const float* values = (const float*)d_in[0];   // [8,4,32768] f32
    const float* coords = (const float*)d_in[1];   // [32768,2] f32

    char* ws = (char*)d_ws;
    unsigned short* Sfrag = (unsigned short*)(ws + 0);          // 192 KB
    unsigned* tileCount   = (unsigned*)(ws + 196608);           // 64 KB  [1024*16] line-padded
    float*    wxy         = (float*)(ws + 262144);              // 1.5 MB [32768*12]
    unsigned* bins        = (unsigned*)(ws + 1835008);          // 768 KB [1024*CAPP]
    unsigned short* Gt    = (unsigned short*)(ws + 2621440);    // 4 MB  [32][256v][256u] bf16
    float*    vt          = (float*)(ws + 6815744);             // 4 MB  [32768][32]
    float*    out         = (float*)d_out;

    void* args[] = {(void*)&coords, (void*)&values, (void*)&Sfrag, (void*)&wxy,
                    (void*)&tileCount, (void*)&bins, (void*)&vt, (void*)&Gt, (void*)&out};
    hipLaunchCooperativeKernel((void*)k_mega, dim3(256), dim3(512), args, 0, stream);
}

// Round 18
// 47.504 us; speedup vs baseline: 2.8956x; 2.8956x over previous
//
#include <hip/hip_runtime.h>
#include <math.h>

#define NPTS 32768
#define CAPP 192
#define CAPC 57
#define SLOT 16          // bins2 slots per (tile, block)
#define SCALE ((float)(256.0 / (2.0 * M_PI)))

typedef __attribute__((ext_vector_type(8))) short short8b;   // 8 bf16
typedef __attribute__((ext_vector_type(4))) float f32x4;

static __device__ __forceinline__ unsigned short f2bf(float x) {
    unsigned u = __float_as_uint(x);
    return (unsigned short)((u + 0x7fffu + ((u >> 16) & 1u)) >> 16);
}

static __device__ __forceinline__ float bessel_i0f(float x) {
    float hx2 = 0.25f * x * x;
    float t = 1.0f, s = 1.0f;
#pragma unroll
    for (int m = 1; m <= 30; ++m) { t *= hx2 * (1.0f / ((float)m * (float)m)); s += t; }
    return s;
}

// ---------- K1: fused front end, 256 blocks ----------
// blocks 0..127  : prep — weights + two-level binning (LDS counters, private regions)
// blocks 128..255: transpose; blocks 128..135 also setup S/Sfrag slices
__global__ __launch_bounds__(256) void k_front(
        const float* __restrict__ coords, const float* __restrict__ values,
        unsigned short* __restrict__ Sfrag, float* __restrict__ wxy,
        unsigned* __restrict__ cnts32, unsigned* __restrict__ bins2,
        float* __restrict__ vt) {
    __shared__ unsigned cnt[1024];                  // prep role
    __shared__ float tile[32][257];                 // transpose role
    __shared__ float axf[128];
    __shared__ float2 sSh[256];
    int blk = blockIdx.x;
    int t = threadIdx.x;

    if (blk < 128) {
        // ---- prep ----
        for (int i = t; i < 1024; i += 256) cnt[i] = 0u;
        __syncthreads();
        int k = blk * 256 + t;
        const float inv_i0a = 1.0f / bessel_i0f(14.04f);  // constant-folds
        float2 cv = *(const float2*)&coords[2 * k];
        float gmx = cv.x * SCALE;
        float gmy = cv.y * SCALE;
        float bxf = floorf(gmx - 3.0f), byf = floorf(gmy - 3.0f);
        float wl[12];
#pragma unroll
        for (int j = 0; j < 6; ++j) {
            float ux = gmx - (bxf + (float)(j + 1));
            float rx = ux * (1.0f / 3.0f);
            float argx = 1.0f - rx * rx;
            wl[j] = (argx > 0.0f) ? bessel_i0f(14.04f * sqrtf(argx)) * inv_i0a : 0.0f;
            float uy = gmy - (byf + (float)(j + 1));
            float ry = uy * (1.0f / 3.0f);
            float argy = 1.0f - ry * ry;
            wl[6 + j] = (argy > 0.0f) ? bessel_i0f(14.04f * sqrtf(argy)) * inv_i0a : 0.0f;
        }
        float4* wp = (float4*)&wxy[k * 12];
        wp[0] = *(const float4*)&wl[0];
        wp[1] = *(const float4*)&wl[4];
        wp[2] = *(const float4*)&wl[8];
        int x0 = (((int)bxf) + 1 + 512) & 255;
        int y0 = (((int)byf) + 1 + 512) & 255;
        int tx0 = x0 >> 3, tx1 = ((x0 + 5) & 255) >> 3;
        int ty0 = y0 >> 3, ty1 = ((y0 + 5) & 255) >> 3;
        int nx = (tx1 == tx0) ? 1 : 2;
        int ny = (ty1 == ty0) ? 1 : 2;
        int txs[2] = {tx0, tx1}, tys[2] = {ty0, ty1};
        for (int i = 0; i < nx; ++i)
            for (int j = 0; j < ny; ++j) {
                int tl = txs[i] * 32 + tys[j];
                unsigned ex = (unsigned)((x0 - 8 * txs[i] + 256) & 255);
                unsigned ey = (unsigned)((y0 - 8 * tys[j] + 256) & 255);
                unsigned pos = atomicAdd(&cnt[tl], 1u);      // LDS atomic, no global state
                if (pos < SLOT)
                    bins2[(tl * 128 + blk) * SLOT + pos] = ((unsigned)k << 16) | (ex << 8) | ey;
            }
        __syncthreads();
        // pack 4 counts per u32; fully overwritten every launch -> no zeroing needed
        unsigned c0 = cnt[4 * t],     c1 = cnt[4 * t + 1];
        unsigned c2 = cnt[4 * t + 2], c3 = cnt[4 * t + 3];
        c0 = c0 > SLOT ? SLOT : c0;  c1 = c1 > SLOT ? SLOT : c1;
        c2 = c2 > SLOT ? SLOT : c2;  c3 = c3 > SLOT ? SLOT : c3;
        cnts32[blk * 256 + t] = c0 | (c1 << 8) | (c2 << 16) | (c3 << 24);
    } else {
        // ---- transpose ----
        int kbase = (blk - 128) * 256;
        for (int img = 0; img < 32; ++img)
            tile[img][t] = values[img * NPTS + kbase + t];
        __syncthreads();
        int img = t & 31;
        int k0 = t >> 5;                   // 0..7
        for (int r = 0; r < 32; ++r) {
            int kl = k0 + r * 8;           // 0..255
            vt[(kbase + kl) * 32 + img] = tile[img][kl];
        }
        // ---- setup slice (blocks 128..135) ----
        int s = blk - 128;
        if (s < 8) {
            if (t < 128) {
                const float inv_i0a = 1.0f / bessel_i0f(14.04f);
                float om = ((float)t - 63.5f) * (1.0f / 256.0f);
                float pj = (float)M_PI * 6.0f * om;
                float tt = sqrtf(14.04f * 14.04f - pj * pj);       // always real
                float kbft = 6.0f * (sinhf(tt) / tt) * inv_i0a;
                axf[t] = 1.0f / kbft;                              // apodization 1D
            }
            __syncthreads();
            float sw, cw;
            __sincosf((float)t * (float)(2.0 * M_PI / 256.0), &sw, &cw);
            float zr = 1.0f, zi = 0.0f, re = 0.0f, im = 0.0f;
            for (int x = 0; x < 128; ++x) {
                float a = axf[x];                // broadcast, conflict-free
                re = fmaf(a, zr, re);
                im = fmaf(a, zi, im);
                float nzr = zr * cw - zi * sw;
                zi = fmaf(zr, sw, zi * cw);
                zr = nzr;
            }
            sSh[t] = make_float2(re, im);
            __syncthreads();
            for (int idx = s * 4096 + t; idx < (s + 1) * 4096; idx += 256) {
                int i   = idx & 7;
                int ln  = (idx >> 3) & 63;
                int ks  = (idx >> 9) & 7;
                int tl  = idx >> 12;
                int si = (32 * ks + 8 * (ln >> 4) + i - 2 * (16 * tl + (ln & 15))) & 255;
                float2 sv = sSh[si];
                Sfrag[idx]         = f2bf(sv.x);
                Sfrag[32768 + idx] = f2bf(sv.y);
                Sfrag[65536 + idx] = f2bf(-sv.y);
            }
        }
    }
}

// ---------- K2: tile gather -> Gt[img][v][u] in bf16 ----------
__global__ __launch_bounds__(256) void k_gather_tile(
        const float* __restrict__ wxy, const float* __restrict__ vt,
        const unsigned* __restrict__ cnts32, const unsigned* __restrict__ bins2,
        unsigned short* __restrict__ Gt) {
    __shared__ unsigned np;
    __shared__ unsigned cnt[64];
    __shared__ unsigned lists[64 * CAPC];   // entry = (k:15 << 16) | (w:16)
    __shared__ unsigned bsh[CAPP];
    __shared__ unsigned short gsh[64][40];  // [cell][img] pad 40
    int tile = blockIdx.x;                  // 0..1023
    int TX = tile >> 5, TY = tile & 31;
    int t = threadIdx.x;
    if (t == 0) np = 0u;
    if (t < 64) cnt[t] = 0u;
    __syncthreads();
    // stage 0: compact this tile's entries from 128 per-block groups
    if (t < 128) {
        unsigned word = cnts32[t * 256 + (tile >> 2)];
        unsigned cb = (word >> ((tile & 3) * 8)) & 0xFFu;
        if (cb) {
            unsigned pos = atomicAdd(&np, cb);
            const unsigned* src = &bins2[(tile * 128 + t) * SLOT];
            for (unsigned e = 0; e < cb; ++e)
                if (pos + e < CAPP) bsh[pos + e] = src[e];
        }
    }
    __syncthreads();
    unsigned n = np;
    if (n > CAPP) n = CAPP;
    // stage A: build per-cell entry lists
    int total = (int)n * 6;
    for (int task = t; task < total; task += 256) {
        int pi = task / 6;
        int jx = task - pi * 6;
        unsigned en = bsh[pi];
        int ex = (int)((en >> 8) & 255u);
        int ey = (int)(en & 255u);
        if (((ex + jx) & 255) < 8) {
            unsigned k = en >> 16;
            float wxv = wxy[k * 12 + jx];
            int lx = ((ex + jx) & 7) << 3;
            unsigned kq = k << 16;
            int jy0, jy1;
            if (ey <= 7) { jy0 = 0; jy1 = (7 - ey < 5) ? 7 - ey : 5; }
            else         { jy0 = 256 - ey; jy1 = 5; }
            for (int jy = jy0; jy <= jy1; ++jy) {
                float w = wxv * wxy[k * 12 + 6 + jy];
                unsigned q = (unsigned)(w * 65535.0f + 0.5f);
                if (q > 65535u) q = 65535u;
                int cl = lx | ((ey + jy) & 7);
                unsigned pos = atomicAdd(&cnt[cl], 1u);    // native u32 LDS atomic
                if (pos < CAPC) lists[cl * CAPC + pos] = kq | q;
            }
        }
    }
    __syncthreads();
    // stage B: thread owns (cell c, 8 images); pure register gather
    int c = t >> 2;
    int ib = (t & 3) * 8;
    unsigned nc = cnt[c];
    if (nc > CAPC) nc = CAPC;
    float acc0 = 0, acc1 = 0, acc2 = 0, acc3 = 0, acc4 = 0, acc5 = 0, acc6 = 0, acc7 = 0;
    for (unsigned e = 0; e < nc; ++e) {
        unsigned en = lists[c * CAPC + e];             // broadcast within quad
        float w = (float)(en & 0xFFFFu) * (1.0f / 65535.0f);
        const float* vp = &vt[(en >> 16) * 32 + ib];
        float4 va = *(const float4*)vp;
        float4 vb = *(const float4*)(vp + 4);
        acc0 += w * va.x; acc1 += w * va.y; acc2 += w * va.z; acc3 += w * va.w;
        acc4 += w * vb.x; acc5 += w * vb.y; acc6 += w * vb.z; acc7 += w * vb.w;
    }
    {
        unsigned short* gp = &gsh[c][ib];
        gp[0] = f2bf(acc0); gp[1] = f2bf(acc1); gp[2] = f2bf(acc2); gp[3] = f2bf(acc3);
        gp[4] = f2bf(acc4); gp[5] = f2bf(acc5); gp[6] = f2bf(acc6); gp[7] = f2bf(acc7);
    }
    __syncthreads();
    // writeout: thread t -> (img = t>>3, vrow = t&7): 16B contiguous store
    {
        int img = t >> 3;
        int vr = t & 7;
        short8b row;
#pragma unroll
        for (int uu = 0; uu < 8; ++uu)
            row[uu] = (short)gsh[(uu << 3) | vr][img];
        *(short8b*)&Gt[img * 65536 + (((TY << 3) + vr) << 8) + (TX << 3)] = row;
    }
}

// ---------- K3: MFMA spectral stage, 1-D grid, XCD-aligned img groups ----------
__global__ __launch_bounds__(512) void k_mmx(const unsigned short* __restrict__ Gt,
                                             const unsigned short* __restrict__ Sfrag,
                                             float* __restrict__ out) {
    __shared__ unsigned short T1[2][16][264];   // [var][p][v^((p&7)<<3)]
    int blk = blockIdx.x;
    int band = blk >> 5;               // 0..7
    int img = blk & 31;                // linear%8 == img%8 -> same-img blocks share an XCD
    int t = threadIdx.x;
    int lane = t & 63;
    int w = t >> 6;                    // wave 0..7
    int g4 = lane >> 4;
    int l15 = lane & 15;

    // ---- stage 1 ----
    {
        int var = w >> 2;              // 0: re, 1: im
        const unsigned short* sf = Sfrag + var * 32768 + band * 4096 + lane * 8;
        short8b a[8];
#pragma unroll
        for (int ks = 0; ks < 8; ++ks)
            a[ks] = *(const short8b*)(sf + ks * 512);
        const unsigned short* gimg = Gt + img * 65536 + 8 * g4;
#pragma unroll
        for (int j = 0; j < 4; ++j) {
            int vtile = (w & 3) + j * 4;
            int v0 = vtile * 16;
            const unsigned short* gb = gimg + (v0 + l15) * 256;
            f32x4 acc = {0.f, 0.f, 0.f, 0.f};
#pragma unroll
            for (int ks = 0; ks < 8; ++ks) {
                short8b b = *(const short8b*)(gb + ks * 32);
                acc = __builtin_amdgcn_mfma_f32_16x16x32_bf16(a[ks], b, acc, 0, 0, 0);
            }
            int vcol = v0 + l15;
#pragma unroll
            for (int r = 0; r < 4; ++r) {
                int p = g4 * 4 + r;
                T1[var][p][vcol ^ ((p & 7) << 3)] = f2bf(acc[r]);
            }
        }
    }
    __syncthreads();

    // ---- stage 2 ----
    {
        int qt = w;
        const unsigned short* sfq = Sfrag + qt * 4096 + lane * 8;
        int swz = (l15 & 7) << 3;
        f32x4 accR = {0.f, 0.f, 0.f, 0.f}, accI = {0.f, 0.f, 0.f, 0.f};
#pragma unroll
        for (int ks = 0; ks < 8; ++ks) {
            int vidx = (32 * ks + 8 * g4) ^ swz;
            short8b aR = *(const short8b*)&T1[0][l15][vidx];
            short8b aI = *(const short8b*)&T1[1][l15][vidx];
            short8b bR = *(const short8b*)(sfq + ks * 512);
            short8b bI = *(const short8b*)(sfq + 32768 + ks * 512);
            short8b bN = *(const short8b*)(sfq + 65536 + ks * 512);
            accR = __builtin_amdgcn_mfma_f32_16x16x32_bf16(aR, bR, accR, 0, 0, 0);
            accR = __builtin_amdgcn_mfma_f32_16x16x32_bf16(aI, bN, accR, 0, 0, 0);
            accI = __builtin_amdgcn_mfma_f32_16x16x32_bf16(aR, bI, accI, 0, 0, 0);
            accI = __builtin_amdgcn_mfma_f32_16x16x32_bf16(aI, bR, accI, 0, 0, 0);
        }
        int q = qt * 16 + l15;
        int b_ = img >> 2, c_ = img & 3;
        int obase = ((b_ ^ 4) * 4 + (c_ ^ 2)) * 128;
#pragma unroll
        for (int r = 0; r < 4; ++r) {
            int p = band * 16 + g4 * 4 + r;
            float re = accR[r], im = accI[r];
            out[((obase + (p ^ 64)) << 7) + (q ^ 64)] = sqrtf(re * re + im * im);
        }
    }
}

extern "C" void kernel_launch(void* const* d_in, const int* in_sizes, int n_in,
                              void* d_out, int out_size, void* d_ws, size_t ws_size,
                              hipStream_t stream) {
    const float* values = (const float*)d_in[0];   // [8,4,32768] f32
    const float* coords = (const float*)d_in[1];   // [32768,2] f32

    char* ws = (char*)d_ws;
    unsigned short* Sfrag = (unsigned short*)(ws + 0);          // 192 KB
    float*    wxy         = (float*)(ws + 262144);              // 1.5 MB [32768*12]
    unsigned* cnts32      = (unsigned*)(ws + 1835008);          // 128 KB [128][256] packed u8x4
    unsigned* bins2       = (unsigned*)(ws + 1966080);          // 8 MB  [1024][128][SLOT]
    unsigned short* Gt    = (unsigned short*)(ws + 10354688);   // 4 MB  [32][256v][256u] bf16
    float*    vt          = (float*)(ws + 14548992);            // 4 MB  [32768][32]

    k_front<<<256, 256, 0, stream>>>(coords, values, Sfrag, wxy, cnts32, bins2, vt);
    k_gather_tile<<<1024, 256, 0, stream>>>(wxy, vt, cnts32, bins2, Gt);
    k_mmx<<<256, 512, 0, stream>>>(Gt, Sfrag, (float*)d_out);
}